// Round 17
// baseline (79.553 us; speedup 1.0000x reference)
//
#include <hip/hip_runtime.h>
#include <hip/hip_bf16.h>

// I2I CrossAttention + gate fusion, MI355X (gfx950).
// B=1, C=128, D*H*W = N = 8192, HEADS=4, DH=32.
// Round 17: attn is TRANS-PIPE-BOUND (16384 v_exp wave-instrs/CU x 8 cyc =
//           54.6us = measured). Hybrid exp: half via v_exp_f32 (trans pipe),
//           half via 3-FMA cubic Taylor on VALU (|logit|<=~0.5 -> rel err
//           6e-4 << bf16 quantization). Everything else = R16.

typedef __attribute__((ext_vector_type(4))) float f32x4;
typedef __attribute__((ext_vector_type(4))) unsigned u32x4;
typedef __attribute__((ext_vector_type(8))) short s16x8;
typedef __attribute__((ext_vector_type(4))) short s16x4;

#define MFMA_BF16(A,B,C) __builtin_amdgcn_mfma_f32_16x16x32_bf16((A),(B),(C),0,0,0)

static __device__ __forceinline__ float fexp2(float x){
  float r; asm("v_exp_f32 %0, %1" : "=v"(r) : "v"(x)); return r;
}
// cubic Taylor 2^x for |x| <~ 0.7 (rel err <= ~6e-4, below bf16 quantization)
static __device__ __forceinline__ float pexp2(float x){
  return fmaf(fmaf(fmaf(0.05550411f, x, 0.24022651f), x, 0.69314718f), x, 1.0f);
}
static __device__ __forceinline__ float frcp(float x){
  float r; asm("v_rcp_f32 %0, %1" : "=v"(r) : "v"(x)); return r;
}
static __device__ __forceinline__ unsigned cvtpk(float lo, float hi){
  unsigned r; asm("v_cvt_pk_bf16_f32 %0, %1, %2" : "=v"(r) : "v"(lo), "v"(hi)); return r;
}
static __device__ __forceinline__ float bf2f(short s){
  return __bfloat162float(__builtin_bit_cast(__hip_bfloat16, s));
}

__device__ __forceinline__ void gll16(const void* g, void* l){
  __builtin_amdgcn_global_load_lds(
      (const __attribute__((address_space(1))) void*)g,
      (__attribute__((address_space(3))) void*)l, 16, 0, 0);
}

// ------------- prep: blocks 0-255 transpose feat1/feat2; 256-703 wprep -------------
__global__ __launch_bounds__(256) void prep(
    const float* __restrict__ f1, const float* __restrict__ f2,
    __hip_bfloat16* __restrict__ F1T, __hip_bfloat16* __restrict__ F2T,
    const float* __restrict__ Wq, const float* __restrict__ Wk,
    const float* __restrict__ Wv, const float* __restrict__ Wo,
    const float* __restrict__ Wg1, const float* __restrict__ Wg2,
    __hip_bfloat16* __restrict__ wout)
{
  __shared__ __hip_bfloat16 tile[64][128];
  int tid = threadIdx.x;
  const float SCQ = 0.17677669529663689f * 1.44269504088896340f;
  if (blockIdx.x >= 256){
    int i = (blockIdx.x-256)*256 + tid;              // 0..114687
    float v;
    if      (i < 16384) v = Wq[i]*SCQ;
    else if (i < 32768) v = Wk[i-16384];
    else if (i < 49152) v = Wv[i-32768];
    else if (i < 65536) v = Wo[i-49152];
    else if (i < 98304) v = Wg1[i-65536];
    else                v = Wg2[i-98304];
    wout[i] = __float2bfloat16(v);
    return;
  }
  const float* in = (blockIdx.x >= 128) ? f2 : f1;
  __hip_bfloat16* out = (blockIdx.x >= 128) ? F2T : F1T;
  int n0 = (blockIdx.x & 127)*64;
  int cq = tid>>4;
  int nq = (tid&15)*4;
  #pragma unroll
  for (int r=0;r<8;r++){
    int c = r*16 + cq;
    f32x4 val = *(const f32x4*)&in[c*8192 + n0 + nq];
    #pragma unroll
    for (int i=0;i<4;i++){
      int n = nq + i;
      tile[n][c ^ ((n&7)<<4)] = __float2bfloat16(val[i]);
    }
  }
  __syncthreads();
  int row = tid>>2;
  int cb  = (tid&3)*32;
  #pragma unroll
  for (int k=0;k<4;k++){
    int c0 = cb + 8*k;
    s16x8 v = *(const s16x8*)&tile[row][c0 ^ ((row&7)<<4)];
    *(s16x8*)&out[(n0+row)*128 + c0] = v;
  }
}

// ---------------- fused Q/K/V projection, 32-n blocks, weight reuse ----------------
__global__ __launch_bounds__(256) void qkv(
    const __hip_bfloat16* __restrict__ F1T, const __hip_bfloat16* __restrict__ F2T,
    const __hip_bfloat16* __restrict__ Wall,
    const float* __restrict__ bq, const float* __restrict__ bk,
    const float* __restrict__ bv,
    __hip_bfloat16* __restrict__ QT, __hip_bfloat16* __restrict__ KT,
    __hip_bfloat16* __restrict__ Vp)
{
  const float SCQ = 0.17677669529663689f * 1.44269504088896340f;
  int y = blockIdx.y;
  const __hip_bfloat16* A  = (y==0) ? F1T : F2T;
  const __hip_bfloat16* Bw = Wall + y*16384;
  const float* bias = (y==0) ? bq : (y==1) ? bk : bv;
  float bscale = (y==0) ? SCQ : 1.f;

  int tid = threadIdx.x;
  int w = tid>>6, lane = tid&63, g = lane>>4, ln = lane&15;
  int n0 = blockIdx.x*32, o0 = w*32;
  f32x4 acc[2][2];                                    // [nj][to]
  acc[0][0]=(f32x4){0,0,0,0}; acc[0][1]=(f32x4){0,0,0,0};
  acc[1][0]=(f32x4){0,0,0,0}; acc[1][1]=(f32x4){0,0,0,0};
  #pragma unroll
  for (int ck=0; ck<4; ck++){
    s16x8 bf0 = *(const s16x8*)&Bw[(o0+ln)*128 + ck*32 + 8*g];
    s16x8 bf1 = *(const s16x8*)&Bw[(o0+16+ln)*128 + ck*32 + 8*g];
    #pragma unroll
    for (int nj=0; nj<2; nj++){
      s16x8 af = *(const s16x8*)&A[(n0+nj*16+ln)*128 + ck*32 + 8*g];
      if (y == 2){
        acc[nj][0] = MFMA_BF16(bf0, af, acc[nj][0]);
        acc[nj][1] = MFMA_BF16(bf1, af, acc[nj][1]);
      } else {
        acc[nj][0] = MFMA_BF16(af, bf0, acc[nj][0]);
        acc[nj][1] = MFMA_BF16(af, bf1, acc[nj][1]);
      }
    }
  }
  if (y == 2){
    // R4-validated permute: granule Gx = (4*(m63>>5) | q) ^ (o&7), pos hb*4+i
    #pragma unroll
    for (int nj=0; nj<2; nj++){
      #pragma unroll
      for (int to=0; to<2; to++){
        f32x4 a = acc[nj][to];
        #pragma unroll
        for (int r=0;r<4;r++){
          int o = o0 + 16*to + 4*g + r;
          int n = n0 + nj*16 + ln;
          int m63 = n & 63, blk = n >> 6;
          int Gx = (((m63>>5)<<2) | ((m63>>2)&3)) ^ (o & 7);
          int col = blk*64 + Gx*8 + ((m63>>4)&1)*4 + (m63&3);
          Vp[(size_t)o*8192 + col] = __float2bfloat16(a[r] + bias[o]);
        }
      }
    }
  } else {
    __hip_bfloat16* outb = (y==0) ? QT : KT;
    float b0 = bias[o0+ln]*bscale, b1 = bias[o0+16+ln]*bscale;
    #pragma unroll
    for (int nj=0; nj<2; nj++){
      #pragma unroll
      for (int to=0; to<2; to++){
        f32x4 a = acc[nj][to];
        float bb = to ? b1 : b0;
        int o = o0 + 16*to + ln;
        #pragma unroll
        for (int r=0;r<4;r++){
          int n = n0 + nj*16 + 4*g + r;
          outb[n*128 + o] = __float2bfloat16(a[r] + bb);
        }
      }
    }
  }
}

// ---------------- fused attention: 8-wave, barrier-free, hybrid trans/VALU exp ----------------
// 1-D grid 512; h=(id&7)>>1 (one head per XCD), nt=(id>>3)*2+(id&1).
// Block: 512 threads = 8 waves; wave w = m-eighth (1024 m), 16 steps of 64m.
// K staged into PRIVATE 4KB LDS region (dbuf, per-wave vmcnt(4), no barriers);
// V direct from global. psum via ones-MFMA. exp split: j<2 trans, j>=2 VALU poly.
__global__ __launch_bounds__(512, 2) void attn17(
    const __hip_bfloat16* __restrict__ QT, const __hip_bfloat16* __restrict__ KT,
    const __hip_bfloat16* __restrict__ Vp, __hip_bfloat16* __restrict__ OT)
{
  __shared__ short stage[2][16384];   // 2 x 32KB: wave w at w*2048 (4KB per buf)

  const int tid = threadIdx.x;
  const int w = tid>>6, lane = tid&63, g = lane>>4, ln = lane&15;
  const int id = blockIdx.x;
  const int h = (id & 7) >> 1;                        // one head per XCD
  const int nbase = (((id >> 3) << 1) | (id & 1)) * 64;

  const __hip_bfloat16* Kh = KT + h*32;
  const __hip_bfloat16* Vh = Vp + (size_t)(h*32)*8192;

  // Q fragments (Q pre-scaled by SCALE*log2e): 64 n, same for all waves
  s16x8 qf[4];
  #pragma unroll
  for (int j=0;j<4;j++)
    qf[j] = *(const s16x8*)&QT[(size_t)(nbase+16*j+ln)*128 + h*32 + 8*g];

  // ---- K staging: wave w stages its own m-eighth (4 segs x 1KB per step) ----
  const __hip_bfloat16* gp[4];
  int ldoff[4];
  #pragma unroll
  for (int u=0; u<4; u++){
    int row = u*16 + (lane>>2);
    int gk  = (lane&3) ^ ((lane>>3)&3);               // source-side K swizzle
    gp[u] = &Kh[(size_t)(w*1024 + row)*128 + 8*gk];
    ldoff[u] = w*2048 + u*512;                        // shorts (1KB per seg)
  }
  short* sb = &stage[0][0];

  #define ISSUE(OFF) { \
    _Pragma("unroll") \
    for (int u=0;u<4;u++){ gll16(gp[u], sb + (OFF) + ldoff[u]); gp[u] += 64*128; } }

  // ---- LDS/global read offsets (shorts), verbatim R7/R12 formulas ----
  const int kloff = ln*32 + ((g ^ ((ln>>1)&3))<<3);   // + r*512, within K region
  int voff[2];
  voff[0] = 8*((g  ) ^ (ln&7));
  voff[1] = 8*((g+4) ^ (ln&7));

  // V direct-from-global base pointers (R11/R12 address equivalence)
  const short* vb[2][2];
  #pragma unroll
  for (int kk=0;kk<2;kk++)
    #pragma unroll
    for (int ct=0;ct<2;ct++)
      vb[kk][ct] = (const short*)Vh + (size_t)(16*ct+ln)*8192 + w*1024 + voff[kk];

  const u32x4 onesw = {0x3F803F80u,0x3F803F80u,0x3F803F80u,0x3F803F80u};
  const s16x8 onesf = __builtin_bit_cast(s16x8, onesw);

  f32x4 acc[2][4];                                     // [ct][j]
  #pragma unroll
  for (int ct=0;ct<2;ct++)
    #pragma unroll
    for (int j=0;j<4;j++) acc[ct][j] = (f32x4){0.f,0.f,0.f,0.f};
  f32x4 accS[4];                                       // ones-MFMA psum
  #pragma unroll
  for (int j=0;j<4;j++) accS[j] = (f32x4){0.f,0.f,0.f,0.f};

  #define CONSUME(CUR, T) { \
    const short* Kl = sb + (CUR) + w*2048; \
    s16x8 kf0 = *(const s16x8*)&Kl[         kloff]; \
    s16x8 kf1 = *(const s16x8*)&Kl[ 512  +  kloff]; \
    s16x8 kf2 = *(const s16x8*)&Kl[1024  +  kloff]; \
    s16x8 kf3 = *(const s16x8*)&Kl[1536  +  kloff]; \
    const int mo = (T)*64; \
    s16x8 vf00 = *(const s16x8*)(vb[0][0] + mo); \
    s16x8 vf01 = *(const s16x8*)(vb[0][1] + mo); \
    s16x8 vf10 = *(const s16x8*)(vb[1][0] + mo); \
    s16x8 vf11 = *(const s16x8*)(vb[1][1] + mo); \
    const f32x4 z = {0.f,0.f,0.f,0.f}; \
    __builtin_amdgcn_s_setprio(1); \
    f32x4 s00 = MFMA_BF16(kf0, qf[0], z), s01 = MFMA_BF16(kf0, qf[1], z); \
    f32x4 s02 = MFMA_BF16(kf0, qf[2], z), s03 = MFMA_BF16(kf0, qf[3], z); \
    f32x4 s10 = MFMA_BF16(kf1, qf[0], z), s11 = MFMA_BF16(kf1, qf[1], z); \
    f32x4 s12 = MFMA_BF16(kf1, qf[2], z), s13 = MFMA_BF16(kf1, qf[3], z); \
    __builtin_amdgcn_s_setprio(0); \
    s16x8 pb0[4]; \
    _Pragma("unroll") \
    for (int j=0;j<4;j++){ \
      f32x4 sa = (j==0)?s00:(j==1)?s01:(j==2)?s02:s03; \
      f32x4 sc = (j==0)?s10:(j==1)?s11:(j==2)?s12:s13; \
      float e0,e1,e2,e3,f0,f1,f2,f3; \
      if (j < 2){ \
        e0=fexp2(sa[0]); e1=fexp2(sa[1]); e2=fexp2(sa[2]); e3=fexp2(sa[3]); \
        f0=fexp2(sc[0]); f1=fexp2(sc[1]); f2=fexp2(sc[2]); f3=fexp2(sc[3]); \
      } else { \
        e0=pexp2(sa[0]); e1=pexp2(sa[1]); e2=pexp2(sa[2]); e3=pexp2(sa[3]); \
        f0=pexp2(sc[0]); f1=pexp2(sc[1]); f2=pexp2(sc[2]); f3=pexp2(sc[3]); \
      } \
      u32x4 pw; \
      pw[0]=cvtpk(e0,e1); pw[1]=cvtpk(e2,e3); pw[2]=cvtpk(f0,f1); pw[3]=cvtpk(f2,f3); \
      pb0[j] = __builtin_bit_cast(s16x8, pw); \
    } \
    __builtin_amdgcn_s_setprio(1); \
    f32x4 s20 = MFMA_BF16(kf2, qf[0], z), s21 = MFMA_BF16(kf2, qf[1], z); \
    f32x4 s22 = MFMA_BF16(kf2, qf[2], z), s23 = MFMA_BF16(kf2, qf[3], z); \
    f32x4 s30 = MFMA_BF16(kf3, qf[0], z), s31 = MFMA_BF16(kf3, qf[1], z); \
    f32x4 s32 = MFMA_BF16(kf3, qf[2], z), s33 = MFMA_BF16(kf3, qf[3], z); \
    __builtin_amdgcn_s_setprio(0); \
    s16x8 pb1[4]; \
    _Pragma("unroll") \
    for (int j=0;j<4;j++){ \
      f32x4 sa = (j==0)?s20:(j==1)?s21:(j==2)?s22:s23; \
      f32x4 sc = (j==0)?s30:(j==1)?s31:(j==2)?s32:s33; \
      float e0,e1,e2,e3,f0,f1,f2,f3; \
      if (j < 2){ \
        e0=fexp2(sa[0]); e1=fexp2(sa[1]); e2=fexp2(sa[2]); e3=fexp2(sa[3]); \
        f0=fexp2(sc[0]); f1=fexp2(sc[1]); f2=fexp2(sc[2]); f3=fexp2(sc[3]); \
      } else { \
        e0=pexp2(sa[0]); e1=pexp2(sa[1]); e2=pexp2(sa[2]); e3=pexp2(sa[3]); \
        f0=pexp2(sc[0]); f1=pexp2(sc[1]); f2=pexp2(sc[2]); f3=pexp2(sc[3]); \
      } \
      u32x4 pw; \
      pw[0]=cvtpk(e0,e1); pw[1]=cvtpk(e2,e3); pw[2]=cvtpk(f0,f1); pw[3]=cvtpk(f2,f3); \
      pb1[j] = __builtin_bit_cast(s16x8, pw); \
    } \
    __builtin_amdgcn_s_setprio(1); \
    _Pragma("unroll") \
    for (int j=0;j<4;j++){ \
      acc[0][j] = MFMA_BF16(vf00, pb0[j], acc[0][j]); \
      acc[1][j] = MFMA_BF16(vf01, pb0[j], acc[1][j]); \
      acc[0][j] = MFMA_BF16(vf10, pb1[j], acc[0][j]); \
      acc[1][j] = MFMA_BF16(vf11, pb1[j], acc[1][j]); \
      accS[j]   = MFMA_BF16(onesf, pb0[j], accS[j]); \
      accS[j]   = MFMA_BF16(onesf, pb1[j], accS[j]); \
    } \
    __builtin_amdgcn_s_setprio(0); \
  }

  ISSUE(0);                                            // step 0 into buf0
  int cur = 0;
  for (int t=0; t<15; ++t){
    ISSUE(16384 - cur);                                // prefetch t+1 into other buf
    asm volatile("s_waitcnt vmcnt(4)" ::: "memory");   // step-t K loads done
    CONSUME(cur, t);
    cur = 16384 - cur;
  }
  asm volatile("s_waitcnt vmcnt(0)" ::: "memory");
  CONSUME(cur, 15);
  #undef CONSUME
  #undef ISSUE

  // ---- 8-way combine through stage scratch; accS[j][0] = psum(n=nbase+16j+ln)
  __syncthreads();
  float* scr = (float*)sb;                             // 7 x 64 x 36 floats (63KB)
  if (w != 0){
    int base = ((w-1)*64 + lane)*36;
    #pragma unroll
    for (int ct=0; ct<2; ct++)
      #pragma unroll
      for (int j=0;j<4;j++)
        *(f32x4*)&scr[base + (ct*4+j)*4] = acc[ct][j];
    #pragma unroll
    for (int j=0;j<4;j++) scr[base+32+j] = accS[j][0];
  }
  __syncthreads();
  if (w == 0){
    float inv[4];
    #pragma unroll
    for (int j=0;j<4;j++){
      float ps = accS[j][0];
      #pragma unroll
      for (int q=0; q<7; q++) ps += scr[(q*64+lane)*36 + 32 + j];
      inv[j] = frcp(ps);
    }
    #pragma unroll
    for (int ct=0; ct<2; ct++){
      #pragma unroll
      for (int j=0;j<4;j++){
        f32x4 o = acc[ct][j];
        #pragma unroll
        for (int q=0; q<7; q++)
          o += *(const f32x4*)&scr[(q*64+lane)*36 + (ct*4+j)*4];
        unsigned lo = cvtpk(o[0]*inv[j], o[1]*inv[j]);
        unsigned hi = cvtpk(o[2]*inv[j], o[3]*inv[j]);
        unsigned long long pk = ((unsigned long long)hi<<32) | lo;
        *(unsigned long long*)&OT[(size_t)(nbase+16*j+ln)*128 + h*32 + 16*ct + 4*g] = pk;
      }
    }
  }
}

// ---------------- fused epilogue: AOT -> G1(relu) -> gate+combine, 32-n blocks ----------------
__global__ __launch_bounds__(256) void tail3(
    const __hip_bfloat16* __restrict__ OT, const __hip_bfloat16* __restrict__ F1T,
    const __hip_bfloat16* __restrict__ WOb, const __hip_bfloat16* __restrict__ WG1b,
    const __hip_bfloat16* __restrict__ WG2b,
    const float* __restrict__ bo, const float* __restrict__ bg1,
    const float* __restrict__ bg2,
    const float* __restrict__ feat1, float* __restrict__ out)
{
  __shared__ __hip_bfloat16 aot[32][128];
  __shared__ __hip_bfloat16 g1[32][128];
  int tid = threadIdx.x;
  int w = tid>>6, lane = tid&63, g = lane>>4, ln = lane&15;
  int n0 = blockIdx.x*32, o0 = w*32;

  // ---- Stage A: AOT = OT*Wo^T + bo -> LDS ----
  {
    f32x4 a[2][2];
    a[0][0]=(f32x4){0,0,0,0}; a[0][1]=(f32x4){0,0,0,0};
    a[1][0]=(f32x4){0,0,0,0}; a[1][1]=(f32x4){0,0,0,0};
    #pragma unroll
    for (int ck=0; ck<4; ck++){
      s16x8 bf0 = *(const s16x8*)&WOb[(o0+ln)*128 + ck*32 + 8*g];
      s16x8 bf1 = *(const s16x8*)&WOb[(o0+16+ln)*128 + ck*32 + 8*g];
      #pragma unroll
      for (int nj=0; nj<2; nj++){
        s16x8 af = *(const s16x8*)&OT[(n0+nj*16+ln)*128 + ck*32 + 8*g];
        a[nj][0] = MFMA_BF16(af, bf0, a[nj][0]);
        a[nj][1] = MFMA_BF16(af, bf1, a[nj][1]);
      }
    }
    float b0 = bo[o0+ln], b1 = bo[o0+16+ln];
    #pragma unroll
    for (int nj=0; nj<2; nj++){
      #pragma unroll
      for (int to=0; to<2; to++){
        f32x4 av = a[nj][to];
        float bb = to ? b1 : b0;
        int o = o0 + 16*to + ln;
        #pragma unroll
        for (int r=0;r<4;r++)
          aot[nj*16 + 4*g + r][o] = __float2bfloat16(av[r] + bb);
      }
    }
  }
  __syncthreads();

  // ---- Stage B: G1 = relu(Wg1*[AOT;F1T] + bg1) -> LDS ----
  {
    f32x4 a[2][2];
    a[0][0]=(f32x4){0,0,0,0}; a[0][1]=(f32x4){0,0,0,0};
    a[1][0]=(f32x4){0,0,0,0}; a[1][1]=(f32x4){0,0,0,0};
    #pragma unroll
    for (int ck=0; ck<8; ck++){
      s16x8 bf0 = *(const s16x8*)&WG1b[(o0+ln)*256 + ck*32 + 8*g];
      s16x8 bf1 = *(const s16x8*)&WG1b[(o0+16+ln)*256 + ck*32 + 8*g];
      #pragma unroll
      for (int nj=0; nj<2; nj++){
        s16x8 af;
        if (ck < 4) af = *(const s16x8*)&aot[nj*16+ln][ck*32 + 8*g];
        else        af = *(const s16x8*)&F1T[(n0+nj*16+ln)*128 + (ck-4)*32 + 8*g];
        a[nj][0] = MFMA_BF16(af, bf0, a[nj][0]);
        a[nj][1] = MFMA_BF16(af, bf1, a[nj][1]);
      }
    }
    float b0 = bg1[o0+ln], b1 = bg1[o0+16+ln];
    #pragma unroll
    for (int nj=0; nj<2; nj++){
      #pragma unroll
      for (int to=0; to<2; to++){
        f32x4 av = a[nj][to];
        float bb = to ? b1 : b0;
        int o = o0 + 16*to + ln;
        #pragma unroll
        for (int r=0;r<4;r++)
          g1[nj*16 + 4*g + r][o] = __float2bfloat16(fmaxf(av[r] + bb, 0.f));
      }
    }
  }
  __syncthreads();

  // ---- Stage C: gate = sigmoid(Wg2*G1 + bg2); out = gate*f1 + (1-gate)*aot ----
  {
    f32x4 a[2][2];
    a[0][0]=(f32x4){0,0,0,0}; a[0][1]=(f32x4){0,0,0,0};
    a[1][0]=(f32x4){0,0,0,0}; a[1][1]=(f32x4){0,0,0,0};
    #pragma unroll
    for (int ck=0; ck<4; ck++){
      s16x8 bf0 = *(const s16x8*)&WG2b[(o0+ln)*128 + ck*32 + 8*g];
      s16x8 bf1 = *(const s16x8*)&WG2b[(o0+16+ln)*128 + ck*32 + 8*g];
      #pragma unroll
      for (int nj=0; nj<2; nj++){
        s16x8 af = *(const s16x8*)&g1[nj*16+ln][ck*32 + 8*g];
        a[nj][0] = MFMA_BF16(af, bf0, a[nj][0]);
        a[nj][1] = MFMA_BF16(af, bf1, a[nj][1]);
      }
    }
    float b0 = bg2[o0+ln], b1 = bg2[o0+16+ln];
    #pragma unroll
    for (int nj=0; nj<2; nj++){
      #pragma unroll
      for (int to=0; to<2; to++){
        f32x4 av = a[nj][to];
        float bb = to ? b1 : b0;
        int o = o0 + 16*to + ln;
        #pragma unroll
        for (int r=0;r<4;r++){
          int nl = nj*16 + 4*g + r;
          int n = n0 + nl;
          float v = av[r] + bb;
          float gt = frcp(1.f + fexp2(-1.44269504f*v));
          float f1v = feat1[(size_t)o*8192 + n];
          float ao = bf2f(__builtin_bit_cast(short, aot[nl][o]));
          out[(size_t)o*8192 + n] = gt*f1v + (1.f - gt)*ao;
        }
      }
    }
  }
}

extern "C" void kernel_launch(void* const* d_in, const int* in_sizes, int n_in,
                              void* d_out, int out_size, void* d_ws, size_t ws_size,
                              hipStream_t stream)
{
  const float* feat1 = (const float*)d_in[0];
  const float* feat2 = (const float*)d_in[1];
  const float* Wq = (const float*)d_in[2];  const float* bq = (const float*)d_in[3];
  const float* Wk = (const float*)d_in[4];  const float* bk = (const float*)d_in[5];
  const float* Wv = (const float*)d_in[6];  const float* bv = (const float*)d_in[7];
  const float* Wo = (const float*)d_in[8];  const float* bo = (const float*)d_in[9];
  const float* Wg1 = (const float*)d_in[10]; const float* bg1 = (const float*)d_in[11];
  const float* Wg2 = (const float*)d_in[12]; const float* bg2 = (const float*)d_in[13];

  __hip_bfloat16* WQb  = (__hip_bfloat16*)d_ws;
  __hip_bfloat16* WKb  = WQb + 16384;
  __hip_bfloat16* WVb  = WQb + 32768;
  __hip_bfloat16* WOb  = WQb + 49152;
  __hip_bfloat16* WG1b = WQb + 65536;
  __hip_bfloat16* WG2b = WQb + 98304;
  __hip_bfloat16* F1T  = WQb + 114688;
  __hip_bfloat16* F2T  = F1T + 1048576;
  __hip_bfloat16* QT   = F1T + 2*1048576;
  __hip_bfloat16* KT   = F1T + 3*1048576;
  __hip_bfloat16* Vbf  = F1T + 4*1048576;
  __hip_bfloat16* OT   = F1T + 5*1048576;

  prep<<<704,256,0,stream>>>(feat1,feat2,F1T,F2T,Wq,Wk,Wv,Wo,Wg1,Wg2,WQb);
  qkv<<<dim3(256,3),256,0,stream>>>(F1T,F2T,WQb,bq,bk,bv,QT,KT,Vbf);
  attn17<<<512,512,0,stream>>>(QT,KT,Vbf,OT);
  tail3<<<256,256,0,stream>>>(OT,F1T,WOb,WG1b,WG2b,bo,bg1,bg2,feat1,(float*)d_out);
}

// Round 18
// 73.799 us; speedup vs baseline: 1.0780x; 1.0780x over previous
//
#include <hip/hip_runtime.h>
#include <hip/hip_bf16.h>

// I2I CrossAttention + gate fusion, MI355X (gfx950).
// B=1, C=128, D*H*W = N = 8192, HEADS=4, DH=32.
// Round 18: R14 base (best total 75.7us) with attn V-prefetch fix: V(t+1)
//           loaded into registers RIGHT AFTER ISSUE(S(t+1)), before the
//           explicit vmcnt(12). In-order vmcnt retirement previously forced
//           the V-use wait to drain the staging prefetch (L2 latency exposed
//           every step); now both prefetch streams stay in flight.

typedef __attribute__((ext_vector_type(4))) float f32x4;
typedef __attribute__((ext_vector_type(4))) unsigned u32x4;
typedef __attribute__((ext_vector_type(8))) short s16x8;
typedef __attribute__((ext_vector_type(4))) short s16x4;

#define MFMA_BF16(A,B,C) __builtin_amdgcn_mfma_f32_16x16x32_bf16((A),(B),(C),0,0,0)

static __device__ __forceinline__ float fexp2(float x){
  float r; asm("v_exp_f32 %0, %1" : "=v"(r) : "v"(x)); return r;
}
static __device__ __forceinline__ float frcp(float x){
  float r; asm("v_rcp_f32 %0, %1" : "=v"(r) : "v"(x)); return r;
}
static __device__ __forceinline__ unsigned cvtpk(float lo, float hi){
  unsigned r; asm("v_cvt_pk_bf16_f32 %0, %1, %2" : "=v"(r) : "v"(lo), "v"(hi)); return r;
}
static __device__ __forceinline__ float bf2f(short s){
  return __bfloat162float(__builtin_bit_cast(__hip_bfloat16, s));
}

__device__ __forceinline__ void gll16(const void* g, void* l){
  __builtin_amdgcn_global_load_lds(
      (const __attribute__((address_space(1))) void*)g,
      (__attribute__((address_space(3))) void*)l, 16, 0, 0);
}

// ------------- prep: blocks 0-255 transpose feat1/feat2; 256-703 wprep -------------
__global__ __launch_bounds__(256) void prep(
    const float* __restrict__ f1, const float* __restrict__ f2,
    __hip_bfloat16* __restrict__ F1T, __hip_bfloat16* __restrict__ F2T,
    const float* __restrict__ Wq, const float* __restrict__ Wk,
    const float* __restrict__ Wv, const float* __restrict__ Wo,
    const float* __restrict__ Wg1, const float* __restrict__ Wg2,
    __hip_bfloat16* __restrict__ wout)
{
  __shared__ __hip_bfloat16 tile[64][128];
  int tid = threadIdx.x;
  const float SCQ = 0.17677669529663689f * 1.44269504088896340f;
  if (blockIdx.x >= 256){
    int i = (blockIdx.x-256)*256 + tid;              // 0..114687
    float v;
    if      (i < 16384) v = Wq[i]*SCQ;
    else if (i < 32768) v = Wk[i-16384];
    else if (i < 49152) v = Wv[i-32768];
    else if (i < 65536) v = Wo[i-49152];
    else if (i < 98304) v = Wg1[i-65536];
    else                v = Wg2[i-98304];
    wout[i] = __float2bfloat16(v);
    return;
  }
  const float* in = (blockIdx.x >= 128) ? f2 : f1;
  __hip_bfloat16* out = (blockIdx.x >= 128) ? F2T : F1T;
  int n0 = (blockIdx.x & 127)*64;
  int cq = tid>>4;
  int nq = (tid&15)*4;
  #pragma unroll
  for (int r=0;r<8;r++){
    int c = r*16 + cq;
    f32x4 val = *(const f32x4*)&in[c*8192 + n0 + nq];
    #pragma unroll
    for (int i=0;i<4;i++){
      int n = nq + i;
      tile[n][c ^ ((n&7)<<4)] = __float2bfloat16(val[i]);
    }
  }
  __syncthreads();
  int row = tid>>2;
  int cb  = (tid&3)*32;
  #pragma unroll
  for (int k=0;k<4;k++){
    int c0 = cb + 8*k;
    s16x8 v = *(const s16x8*)&tile[row][c0 ^ ((row&7)<<4)];
    *(s16x8*)&out[(n0+row)*128 + c0] = v;
  }
}

// ---------------- fused Q/K/V projection, 32-n blocks, weight reuse ----------------
__global__ __launch_bounds__(256) void qkv(
    const __hip_bfloat16* __restrict__ F1T, const __hip_bfloat16* __restrict__ F2T,
    const __hip_bfloat16* __restrict__ Wall,
    const float* __restrict__ bq, const float* __restrict__ bk,
    const float* __restrict__ bv,
    __hip_bfloat16* __restrict__ QT, __hip_bfloat16* __restrict__ KT,
    __hip_bfloat16* __restrict__ Vp)
{
  const float SCQ = 0.17677669529663689f * 1.44269504088896340f;
  int y = blockIdx.y;
  const __hip_bfloat16* A  = (y==0) ? F1T : F2T;
  const __hip_bfloat16* Bw = Wall + y*16384;
  const float* bias = (y==0) ? bq : (y==1) ? bk : bv;
  float bscale = (y==0) ? SCQ : 1.f;

  int tid = threadIdx.x;
  int w = tid>>6, lane = tid&63, g = lane>>4, ln = lane&15;
  int n0 = blockIdx.x*32, o0 = w*32;
  f32x4 acc[2][2];                                    // [nj][to]
  acc[0][0]=(f32x4){0,0,0,0}; acc[0][1]=(f32x4){0,0,0,0};
  acc[1][0]=(f32x4){0,0,0,0}; acc[1][1]=(f32x4){0,0,0,0};
  #pragma unroll
  for (int ck=0; ck<4; ck++){
    s16x8 bf0 = *(const s16x8*)&Bw[(o0+ln)*128 + ck*32 + 8*g];
    s16x8 bf1 = *(const s16x8*)&Bw[(o0+16+ln)*128 + ck*32 + 8*g];
    #pragma unroll
    for (int nj=0; nj<2; nj++){
      s16x8 af = *(const s16x8*)&A[(n0+nj*16+ln)*128 + ck*32 + 8*g];
      if (y == 2){
        acc[nj][0] = MFMA_BF16(bf0, af, acc[nj][0]);
        acc[nj][1] = MFMA_BF16(bf1, af, acc[nj][1]);
      } else {
        acc[nj][0] = MFMA_BF16(af, bf0, acc[nj][0]);
        acc[nj][1] = MFMA_BF16(af, bf1, acc[nj][1]);
      }
    }
  }
  if (y == 2){
    // R4-validated permute: granule Gx = (4*(m63>>5) | q) ^ (o&7), pos hb*4+i
    #pragma unroll
    for (int nj=0; nj<2; nj++){
      #pragma unroll
      for (int to=0; to<2; to++){
        f32x4 a = acc[nj][to];
        #pragma unroll
        for (int r=0;r<4;r++){
          int o = o0 + 16*to + 4*g + r;
          int n = n0 + nj*16 + ln;
          int m63 = n & 63, blk = n >> 6;
          int Gx = (((m63>>5)<<2) | ((m63>>2)&3)) ^ (o & 7);
          int col = blk*64 + Gx*8 + ((m63>>4)&1)*4 + (m63&3);
          Vp[(size_t)o*8192 + col] = __float2bfloat16(a[r] + bias[o]);
        }
      }
    }
  } else {
    __hip_bfloat16* outb = (y==0) ? QT : KT;
    float b0 = bias[o0+ln]*bscale, b1 = bias[o0+16+ln]*bscale;
    #pragma unroll
    for (int nj=0; nj<2; nj++){
      #pragma unroll
      for (int to=0; to<2; to++){
        f32x4 a = acc[nj][to];
        float bb = to ? b1 : b0;
        int o = o0 + 16*to + ln;
        #pragma unroll
        for (int r=0;r<4;r++){
          int n = n0 + nj*16 + 4*g + r;
          outb[n*128 + o] = __float2bfloat16(a[r] + bb);
        }
      }
    }
  }
}

// ---------------- fused attention: barrier-free, K-staged, V reg-prefetched ----------------
// Block: 256 threads = 4 waves; wave w = m-quarter (2048 m), shared 64-n tile.
// Grid (128,4) = 512 blocks (2/CU). 32 steps of 64m. K staged into PRIVATE 4KB
// LDS region (dbuf); V(t+1) into registers, issued BEFORE the vmcnt(12) so
// both prefetch streams stay in flight (in-order vmcnt retirement).
__global__ __launch_bounds__(256, 2) void attn18(
    const __hip_bfloat16* __restrict__ QT, const __hip_bfloat16* __restrict__ KT,
    const __hip_bfloat16* __restrict__ Vp, __hip_bfloat16* __restrict__ OT)
{
  __shared__ short stage[2][8192];    // 2 x 16KB: K only; wave w at w*2048 (4KB)

  const int tid = threadIdx.x;
  const int w = tid>>6, lane = tid&63, g = lane>>4, ln = lane&15;
  const int h = blockIdx.y;
  const int nbase = blockIdx.x*64;

  const __hip_bfloat16* Kh = KT + h*32;
  const __hip_bfloat16* Vh = Vp + (size_t)(h*32)*8192;

  s16x8 qf[4];
  #pragma unroll
  for (int j=0;j<4;j++)
    qf[j] = *(const s16x8*)&QT[(size_t)(nbase+16*j+ln)*128 + h*32 + 8*g];

  const __hip_bfloat16* gp[4];
  int ldoff[4];
  #pragma unroll
  for (int u=0; u<4; u++){
    int row = u*16 + (lane>>2);
    int gk  = (lane&3) ^ ((lane>>3)&3);               // source-side K swizzle
    gp[u] = &Kh[(size_t)(w*2048 + row)*128 + 8*gk];
    ldoff[u] = w*2048 + u*512;                        // shorts (1KB per seg)
  }
  short* sb = &stage[0][0];

  #define ISSUE(OFF) { \
    _Pragma("unroll") \
    for (int u=0;u<4;u++){ gll16(gp[u], sb + (OFF) + ldoff[u]); gp[u] += 64*128; } }

  const int kloff = ln*32 + ((g ^ ((ln>>1)&3))<<3);   // + r*512, within K region
  int voff[2];
  voff[0] = 8*((g  ) ^ (ln&7));
  voff[1] = 8*((g+4) ^ (ln&7));

  const short* vb[2][2];
  #pragma unroll
  for (int kk=0;kk<2;kk++)
    #pragma unroll
    for (int ct=0;ct<2;ct++)
      vb[kk][ct] = (const short*)Vh + (size_t)(16*ct+ln)*8192 + w*2048 + voff[kk];

  const u32x4 onesw = {0x3F803F80u,0x3F803F80u,0x3F803F80u,0x3F803F80u};
  const s16x8 onesf = __builtin_bit_cast(s16x8, onesw);

  f32x4 acc[2][4];                                     // [ct][j]
  #pragma unroll
  for (int ct=0;ct<2;ct++)
    #pragma unroll
    for (int j=0;j<4;j++) acc[ct][j] = (f32x4){0.f,0.f,0.f,0.f};
  f32x4 accS[4];                                       // ones-MFMA psum
  #pragma unroll
  for (int j=0;j<4;j++) accS[j] = (f32x4){0.f,0.f,0.f,0.f};

  #define VLOAD(D00,D01,D10,D11,T) { \
    const int mo = (T)*64; \
    D00 = *(const s16x8*)(vb[0][0] + mo); \
    D01 = *(const s16x8*)(vb[0][1] + mo); \
    D10 = *(const s16x8*)(vb[1][0] + mo); \
    D11 = *(const s16x8*)(vb[1][1] + mo); }

  #define CONSUME(CUR, V00,V01,V10,V11) { \
    const short* Kl = sb + (CUR) + w*2048; \
    s16x8 kf0 = *(const s16x8*)&Kl[         kloff]; \
    s16x8 kf1 = *(const s16x8*)&Kl[ 512  +  kloff]; \
    s16x8 kf2 = *(const s16x8*)&Kl[1024  +  kloff]; \
    s16x8 kf3 = *(const s16x8*)&Kl[1536  +  kloff]; \
    const f32x4 z = {0.f,0.f,0.f,0.f}; \
    __builtin_amdgcn_s_setprio(1); \
    f32x4 s00 = MFMA_BF16(kf0, qf[0], z), s01 = MFMA_BF16(kf0, qf[1], z); \
    f32x4 s02 = MFMA_BF16(kf0, qf[2], z), s03 = MFMA_BF16(kf0, qf[3], z); \
    f32x4 s10 = MFMA_BF16(kf1, qf[0], z), s11 = MFMA_BF16(kf1, qf[1], z); \
    f32x4 s12 = MFMA_BF16(kf1, qf[2], z), s13 = MFMA_BF16(kf1, qf[3], z); \
    __builtin_amdgcn_s_setprio(0); \
    s16x8 pb0[4]; \
    _Pragma("unroll") \
    for (int j=0;j<4;j++){ \
      f32x4 sa = (j==0)?s00:(j==1)?s01:(j==2)?s02:s03; \
      f32x4 sc = (j==0)?s10:(j==1)?s11:(j==2)?s12:s13; \
      float e0=fexp2(sa[0]), e1=fexp2(sa[1]), e2=fexp2(sa[2]), e3=fexp2(sa[3]); \
      float f0=fexp2(sc[0]), f1=fexp2(sc[1]), f2=fexp2(sc[2]), f3=fexp2(sc[3]); \
      u32x4 pw; \
      pw[0]=cvtpk(e0,e1); pw[1]=cvtpk(e2,e3); pw[2]=cvtpk(f0,f1); pw[3]=cvtpk(f2,f3); \
      pb0[j] = __builtin_bit_cast(s16x8, pw); \
    } \
    __builtin_amdgcn_s_setprio(1); \
    f32x4 s20 = MFMA_BF16(kf2, qf[0], z), s21 = MFMA_BF16(kf2, qf[1], z); \
    f32x4 s22 = MFMA_BF16(kf2, qf[2], z), s23 = MFMA_BF16(kf2, qf[3], z); \
    f32x4 s30 = MFMA_BF16(kf3, qf[0], z), s31 = MFMA_BF16(kf3, qf[1], z); \
    f32x4 s32 = MFMA_BF16(kf3, qf[2], z), s33 = MFMA_BF16(kf3, qf[3], z); \
    __builtin_amdgcn_s_setprio(0); \
    s16x8 pb1[4]; \
    _Pragma("unroll") \
    for (int j=0;j<4;j++){ \
      f32x4 sa = (j==0)?s20:(j==1)?s21:(j==2)?s22:s23; \
      f32x4 sc = (j==0)?s30:(j==1)?s31:(j==2)?s32:s33; \
      float e0=fexp2(sa[0]), e1=fexp2(sa[1]), e2=fexp2(sa[2]), e3=fexp2(sa[3]); \
      float f0=fexp2(sc[0]), f1=fexp2(sc[1]), f2=fexp2(sc[2]), f3=fexp2(sc[3]); \
      u32x4 pw; \
      pw[0]=cvtpk(e0,e1); pw[1]=cvtpk(e2,e3); pw[2]=cvtpk(f0,f1); pw[3]=cvtpk(f2,f3); \
      pb1[j] = __builtin_bit_cast(s16x8, pw); \
    } \
    __builtin_amdgcn_s_setprio(1); \
    _Pragma("unroll") \
    for (int j=0;j<4;j++){ \
      acc[0][j] = MFMA_BF16(V00, pb0[j], acc[0][j]); \
      acc[1][j] = MFMA_BF16(V01, pb0[j], acc[1][j]); \
      acc[0][j] = MFMA_BF16(V10, pb1[j], acc[0][j]); \
      acc[1][j] = MFMA_BF16(V11, pb1[j], acc[1][j]); \
      accS[j]   = MFMA_BF16(onesf, pb0[j], accS[j]); \
      accS[j]   = MFMA_BF16(onesf, pb1[j], accS[j]); \
    } \
    __builtin_amdgcn_s_setprio(0); \
  }

  s16x8 vn00, vn01, vn10, vn11;
  ISSUE(0);                                            // S(0)
  VLOAD(vn00,vn01,vn10,vn11, 0);                       // V(0)
  int cur = 0;
  for (int t=0; t<31; ++t){
    s16x8 vu00=vn00, vu01=vn01, vu10=vn10, vu11=vn11;  // V(t) (SSA-renamed)
    ISSUE(8192 - cur);                                 // S(t+1)
    VLOAD(vn00,vn01,vn10,vn11, t+1);                   // V(t+1)
    asm volatile("s_waitcnt vmcnt(12)" ::: "memory");  // retire S(t) only
    CONSUME(cur, vu00,vu01,vu10,vu11);
    cur = 8192 - cur;
  }
  asm volatile("s_waitcnt vmcnt(4)" ::: "memory");     // S(31) done
  CONSUME(cur, vn00,vn01,vn10,vn11);
  #undef CONSUME
  #undef VLOAD
  #undef ISSUE

  // ---- 4-way combine through stage scratch; accS[j][0] = psum(n=nbase+16j+ln)
  asm volatile("s_waitcnt vmcnt(0)" ::: "memory");     // drain before scr reuse
  __syncthreads();
  float* scr = (float*)sb;                             // 3 x 64 x 36 floats (27KB)
  if (w != 0){
    int base = ((w-1)*64 + lane)*36;
    #pragma unroll
    for (int ct=0; ct<2; ct++)
      #pragma unroll
      for (int j=0;j<4;j++)
        *(f32x4*)&scr[base + (ct*4+j)*4] = acc[ct][j];
    #pragma unroll
    for (int j=0;j<4;j++) scr[base+32+j] = accS[j][0];
  }
  __syncthreads();
  if (w == 0){
    float inv[4];
    #pragma unroll
    for (int j=0;j<4;j++){
      float ps = accS[j][0];
      #pragma unroll
      for (int q=0; q<3; q++) ps += scr[(q*64+lane)*36 + 32 + j];
      inv[j] = frcp(ps);
    }
    #pragma unroll
    for (int ct=0; ct<2; ct++){
      #pragma unroll
      for (int j=0;j<4;j++){
        f32x4 o = acc[ct][j];
        #pragma unroll
        for (int q=0; q<3; q++)
          o += *(const f32x4*)&scr[(q*64+lane)*36 + (ct*4+j)*4];
        unsigned lo = cvtpk(o[0]*inv[j], o[1]*inv[j]);
        unsigned hi = cvtpk(o[2]*inv[j], o[3]*inv[j]);
        unsigned long long pk = ((unsigned long long)hi<<32) | lo;
        *(unsigned long long*)&OT[(size_t)(nbase+16*j+ln)*128 + h*32 + 16*ct + 4*g] = pk;
      }
    }
  }
}

// ---------------- fused epilogue: AOT -> G1(relu) -> gate+combine, 32-n blocks ----------------
__global__ __launch_bounds__(256) void tail3(
    const __hip_bfloat16* __restrict__ OT, const __hip_bfloat16* __restrict__ F1T,
    const __hip_bfloat16* __restrict__ WOb, const __hip_bfloat16* __restrict__ WG1b,
    const __hip_bfloat16* __restrict__ WG2b,
    const float* __restrict__ bo, const float* __restrict__ bg1,
    const float* __restrict__ bg2,
    const float* __restrict__ feat1, float* __restrict__ out)
{
  __shared__ __hip_bfloat16 aot[32][128];
  __shared__ __hip_bfloat16 g1[32][128];
  int tid = threadIdx.x;
  int w = tid>>6, lane = tid&63, g = lane>>4, ln = lane&15;
  int n0 = blockIdx.x*32, o0 = w*32;

  // ---- Stage A: AOT = OT*Wo^T + bo -> LDS ----
  {
    f32x4 a[2][2];
    a[0][0]=(f32x4){0,0,0,0}; a[0][1]=(f32x4){0,0,0,0};
    a[1][0]=(f32x4){0,0,0,0}; a[1][1]=(f32x4){0,0,0,0};
    #pragma unroll
    for (int ck=0; ck<4; ck++){
      s16x8 bf0 = *(const s16x8*)&WOb[(o0+ln)*128 + ck*32 + 8*g];
      s16x8 bf1 = *(const s16x8*)&WOb[(o0+16+ln)*128 + ck*32 + 8*g];
      #pragma unroll
      for (int nj=0; nj<2; nj++){
        s16x8 af = *(const s16x8*)&OT[(n0+nj*16+ln)*128 + ck*32 + 8*g];
        a[nj][0] = MFMA_BF16(af, bf0, a[nj][0]);
        a[nj][1] = MFMA_BF16(af, bf1, a[nj][1]);
      }
    }
    float b0 = bo[o0+ln], b1 = bo[o0+16+ln];
    #pragma unroll
    for (int nj=0; nj<2; nj++){
      #pragma unroll
      for (int to=0; to<2; to++){
        f32x4 av = a[nj][to];
        float bb = to ? b1 : b0;
        int o = o0 + 16*to + ln;
        #pragma unroll
        for (int r=0;r<4;r++)
          aot[nj*16 + 4*g + r][o] = __float2bfloat16(av[r] + bb);
      }
    }
  }
  __syncthreads();

  // ---- Stage B: G1 = relu(Wg1*[AOT;F1T] + bg1) -> LDS ----
  {
    f32x4 a[2][2];
    a[0][0]=(f32x4){0,0,0,0}; a[0][1]=(f32x4){0,0,0,0};
    a[1][0]=(f32x4){0,0,0,0}; a[1][1]=(f32x4){0,0,0,0};
    #pragma unroll
    for (int ck=0; ck<8; ck++){
      s16x8 bf0 = *(const s16x8*)&WG1b[(o0+ln)*256 + ck*32 + 8*g];
      s16x8 bf1 = *(const s16x8*)&WG1b[(o0+16+ln)*256 + ck*32 + 8*g];
      #pragma unroll
      for (int nj=0; nj<2; nj++){
        s16x8 af;
        if (ck < 4) af = *(const s16x8*)&aot[nj*16+ln][ck*32 + 8*g];
        else        af = *(const s16x8*)&F1T[(n0+nj*16+ln)*128 + (ck-4)*32 + 8*g];
        a[nj][0] = MFMA_BF16(af, bf0, a[nj][0]);
        a[nj][1] = MFMA_BF16(af, bf1, a[nj][1]);
      }
    }
    float b0 = bg1[o0+ln], b1 = bg1[o0+16+ln];
    #pragma unroll
    for (int nj=0; nj<2; nj++){
      #pragma unroll
      for (int to=0; to<2; to++){
        f32x4 av = a[nj][to];
        float bb = to ? b1 : b0;
        int o = o0 + 16*to + ln;
        #pragma unroll
        for (int r=0;r<4;r++)
          g1[nj*16 + 4*g + r][o] = __float2bfloat16(fmaxf(av[r] + bb, 0.f));
      }
    }
  }
  __syncthreads();

  // ---- Stage C: gate = sigmoid(Wg2*G1 + bg2); out = gate*f1 + (1-gate)*aot ----
  {
    f32x4 a[2][2];
    a[0][0]=(f32x4){0,0,0,0}; a[0][1]=(f32x4){0,0,0,0};
    a[1][0]=(f32x4){0,0,0,0}; a[1][1]=(f32x4){0,0,0,0};
    #pragma unroll
    for (int ck=0; ck<4; ck++){
      s16x8 bf0 = *(const s16x8*)&WG2b[(o0+ln)*128 + ck*32 + 8*g];
      s16x8 bf1 = *(const s16x8*)&WG2b[(o0+16+ln)*128 + ck*32 + 8*g];
      #pragma unroll
      for (int nj=0; nj<2; nj++){
        s16x8 af = *(const s16x8*)&g1[nj*16+ln][ck*32 + 8*g];
        a[nj][0] = MFMA_BF16(af, bf0, a[nj][0]);
        a[nj][1] = MFMA_BF16(af, bf1, a[nj][1]);
      }
    }
    float b0 = bg2[o0+ln], b1 = bg2[o0+16+ln];
    #pragma unroll
    for (int nj=0; nj<2; nj++){
      #pragma unroll
      for (int to=0; to<2; to++){
        f32x4 av = a[nj][to];
        float bb = to ? b1 : b0;
        int o = o0 + 16*to + ln;
        #pragma unroll
        for (int r=0;r<4;r++){
          int nl = nj*16 + 4*g + r;
          int n = n0 + nl;
          float v = av[r] + bb;
          float gt = frcp(1.f + fexp2(-1.44269504f*v));
          float f1v = feat1[(size_t)o*8192 + n];
          float ao = bf2f(__builtin_bit_cast(short, aot[nl][o]));
          out[(size_t)o*8192 + n] = gt*f1v + (1.f - gt)*ao;
        }
      }
    }
  }
}

extern "C" void kernel_launch(void* const* d_in, const int* in_sizes, int n_in,
                              void* d_out, int out_size, void* d_ws, size_t ws_size,
                              hipStream_t stream)
{
  const float* feat1 = (const float*)d_in[0];
  const float* feat2 = (const float*)d_in[1];
  const float* Wq = (const float*)d_in[2];  const float* bq = (const float*)d_in[3];
  const float* Wk = (const float*)d_in[4];  const float* bk = (const float*)d_in[5];
  const float* Wv = (const float*)d_in[6];  const float* bv = (const float*)d_in[7];
  const float* Wo = (const float*)d_in[8];  const float* bo = (const float*)d_in[9];
  const float* Wg1 = (const float*)d_in[10]; const float* bg1 = (const float*)d_in[11];
  const float* Wg2 = (const float*)d_in[12]; const float* bg2 = (const float*)d_in[13];

  __hip_bfloat16* WQb  = (__hip_bfloat16*)d_ws;
  __hip_bfloat16* WKb  = WQb + 16384;
  __hip_bfloat16* WVb  = WQb + 32768;
  __hip_bfloat16* WOb  = WQb + 49152;
  __hip_bfloat16* WG1b = WQb + 65536;
  __hip_bfloat16* WG2b = WQb + 98304;
  __hip_bfloat16* F1T  = WQb + 114688;
  __hip_bfloat16* F2T  = F1T + 1048576;
  __hip_bfloat16* QT   = F1T + 2*1048576;
  __hip_bfloat16* KT   = F1T + 3*1048576;
  __hip_bfloat16* Vbf  = F1T + 4*1048576;
  __hip_bfloat16* OT   = F1T + 5*1048576;

  prep<<<704,256,0,stream>>>(feat1,feat2,F1T,F2T,Wq,Wk,Wv,Wo,Wg1,Wg2,WQb);
  qkv<<<dim3(256,3),256,0,stream>>>(F1T,F2T,WQb,bq,bk,bv,QT,KT,Vbf);
  attn18<<<dim3(128,4),256,0,stream>>>(QT,KT,Vbf,OT);
  tail3<<<256,256,0,stream>>>(OT,F1T,WOb,WG1b,WG2b,bo,bg1,bg2,feat1,(float*)d_out);
}